// Round 8
// baseline (95.143 us; speedup 1.0000x reference)
//
#include <hip/hip_runtime.h>
#include <hip/hip_bf16.h>

#define DIM      512
#define EDIM     1024
#define OUTD     512
#define BATCH    4
#define LSEQ     4096
#define MROWS    (BATCH * LSEQ)   // 16384
#define NCHUNK   64
#define CHUNK    (LSEQ / NCHUNK)  // 64

typedef __attribute__((ext_vector_type(8))) __bf16 bf16x8;
typedef __attribute__((ext_vector_type(4))) float  f32x4;

static __device__ __forceinline__ ushort f2b(float f) {
    uint x = __float_as_uint(f);
    x += 0x7fff + ((x >> 16) & 1);           // round-to-nearest-even
    return (ushort)(x >> 16);
}
static __device__ __forceinline__ float b2f(ushort u) {
    return __uint_as_float(((uint)u) << 16);
}
static __device__ __forceinline__ float sigmoidf(float x) {
    return 1.0f / (1.0f + expf(-x));
}

// ---------------------------------------------------------------- prep ----
// blocks [0,512):    beta -> betaT (bf16, LDS 32x32 tiles)
// blocks [512,1024): eta  -> etaT  (bf16, LDS 32x32 tiles)
// block 1024: p,q from logits
__global__ void prep_kernel(const float* __restrict__ beta,
                            const float* __restrict__ eta,
                            const float* __restrict__ la,
                            const float* __restrict__ ld,
                            ushort* __restrict__ betaT,
                            ushort* __restrict__ etaT,
                            float* __restrict__ p,
                            float* __restrict__ q) {
    __shared__ float tf[32][33];
    int blk = blockIdx.x;
    if (blk < 512) {                         // beta transpose
        int tr = blk >> 5, tc = blk & 31;    // tr over K(512), tc over E(1024)
        int r = threadIdx.x >> 3, c4 = (threadIdx.x & 7) * 4;
        float4 v = *(const float4*)(beta + (size_t)(tr * 32 + r) * EDIM + tc * 32 + c4);
        tf[r][c4 + 0] = v.x; tf[r][c4 + 1] = v.y;
        tf[r][c4 + 2] = v.z; tf[r][c4 + 3] = v.w;
        __syncthreads();
        ushort4 o;
        o.x = f2b(tf[c4 + 0][r]); o.y = f2b(tf[c4 + 1][r]);
        o.z = f2b(tf[c4 + 2][r]); o.w = f2b(tf[c4 + 3][r]);
        *(ushort4*)(betaT + (size_t)(tc * 32 + r) * DIM + tr * 32 + c4) = o;
    } else if (blk < 1024) {                 // eta transpose
        int tile = blk - 512;
        int tr = tile >> 4, tc = tile & 15;  // tr over E(1024), tc over O(512)
        int r = threadIdx.x >> 3, c4 = (threadIdx.x & 7) * 4;
        float4 v = *(const float4*)(eta + (size_t)(tr * 32 + r) * OUTD + tc * 32 + c4);
        tf[r][c4 + 0] = v.x; tf[r][c4 + 1] = v.y;
        tf[r][c4 + 2] = v.z; tf[r][c4 + 3] = v.w;
        __syncthreads();
        ushort4 o;
        o.x = f2b(tf[c4 + 0][r]); o.y = f2b(tf[c4 + 1][r]);
        o.z = f2b(tf[c4 + 2][r]); o.w = f2b(tf[c4 + 3][r]);
        *(ushort4*)(etaT + (size_t)(tc * 32 + r) * EDIM + tr * 32 + c4) = o;
    } else {
        #pragma unroll
        for (int j = 0; j < 4; ++j) {
            int e = threadIdx.x * 4 + j;
            float a = sigmoidf(la[e]);
            float d = sigmoidf(ld[e]);
            p[e] = a;
            q[e] = 1.0f - a * d;
        }
    }
}

// ---------------------- GEMM1: 128x128, fp32-A fused cvt, fused agg -------
// u[M,E] = cvt_bf16(emb[M,K]) @ betaT[E,K]^T.  m97 structure (32/48 KB LDS,
// 4 waves, 3+ blocks/CU so cross-block TLP hides staging latency - m114).
// A: reg-staged fp32 (8x dwordx4 issued at loop top = full compute phase of
//    cover), cvt -> ds_write_b128 into the SAME linear layout the bf16
//    gload_lds path used (source pre-swizzled identically). vmcnt(8) lands
//    A only (FIFO: A issued before B's 8 gload_lds).
// B: double-buffered global_load_lds (16B), pre-swizzled source.
__global__ __launch_bounds__(256) void gemm_f32a(const float* __restrict__ A,
                                                 const ushort* __restrict__ Bt,
                                                 ushort* __restrict__ Cv,
                                                 const float* __restrict__ qv,
                                                 float* __restrict__ aggp,
                                                 int M, int N, int K,
                                                 int ncolShift) {
    __shared__ char smem[49152];   // A bf16 [0,16K) ; B bufs [16K,32K),[32K,48K)
    const int tid  = threadIdx.x;
    const int lane = tid & 63;
    const int wid  = tid >> 6;
    const int wr   = wid >> 1, wc = wid & 1;
    const int l15  = lane & 15;
    const int l4   = lane >> 4;

    const int nwg   = gridDim.x;
    const int flat  = (blockIdx.x & 7) * (nwg >> 3) + (blockIdx.x >> 3);
    const int rowBase = (flat >> ncolShift) << 7;
    const int colBase = (flat & ((1 << ncolShift) - 1)) << 7;

    f32x4 acc[4][4] = {};
    float4 aR[4][2];

    const int nkb = K >> 6;   // 8

    // per-chunk source map (identical pre-swizzle to the bf16 path)
    int crow[4], ccol[4];
    #pragma unroll
    for (int r = 0; r < 4; ++r) {
        int c = r * 256 + tid;
        crow[r] = c >> 3;
        ccol[r] = (c & 7) ^ (crow[r] & 7);
    }

    auto ISSUE_A = [&](int kb) {
        #pragma unroll
        for (int r = 0; r < 4; ++r) {
            const float* ga = A + (size_t)(rowBase + crow[r]) * K + kb * 64 + ccol[r] * 8;
            aR[r][0] = *(const float4*)ga;
            aR[r][1] = *(const float4*)(ga + 4);
        }
    };
    auto ISSUE_B = [&](int kb) {
        char* dst = smem + 16384 + (kb & 1) * 16384;
        #pragma unroll
        for (int r = 0; r < 4; ++r) {
            const ushort* gb = Bt + (size_t)(colBase + crow[r]) * K + kb * 64 + ccol[r] * 8;
            __builtin_amdgcn_global_load_lds(
                (const __attribute__((address_space(1))) void*)gb,
                (__attribute__((address_space(3))) void*)(dst + (r * 256 + tid) * 16),
                16, 0, 0);
        }
    };
    auto WRITE_A = [&]() {
        #pragma unroll
        for (int r = 0; r < 4; ++r) {
            uint4 v;
            v.x = (uint)f2b(aR[r][0].x) | ((uint)f2b(aR[r][0].y) << 16);
            v.y = (uint)f2b(aR[r][0].z) | ((uint)f2b(aR[r][0].w) << 16);
            v.z = (uint)f2b(aR[r][1].x) | ((uint)f2b(aR[r][1].y) << 16);
            v.w = (uint)f2b(aR[r][1].z) | ((uint)f2b(aR[r][1].w) << 16);
            *(uint4*)(smem + (r * 256 + tid) * 16) = v;
        }
    };

    // ---- prologue: tile 0
    ISSUE_A(0);
    ISSUE_B(0);
    asm volatile("s_waitcnt vmcnt(8)" ::: "memory");   // A landed (B out)
    WRITE_A();
    asm volatile("s_waitcnt vmcnt(0) lgkmcnt(0)" ::: "memory");
    __builtin_amdgcn_s_barrier();

    for (int kb = 0; kb < nkb; ++kb) {
        const int kn = (kb < nkb - 1) ? kb + 1 : kb;   // clamped (uniform codegen)
        ISSUE_A(kn);                                   // 8 dwordx4, covered by compute
        ISSUE_B(kn);                                   // 8 gload_lds -> other buf
        const char* bbuf = smem + 16384 + (kb & 1) * 16384;
        #pragma unroll
        for (int kk = 0; kk < 2; ++kk) {
            bf16x8 af[4], bfr[4];
            #pragma unroll
            for (int m = 0; m < 4; ++m) {
                int row   = wr * 64 + m * 16 + l15;
                int kbyte = kk * 64 + l4 * 16;
                int addr  = row * 128 + (kbyte ^ ((row & 7) << 4));
                af[m] = *(const bf16x8*)(smem + addr);
            }
            #pragma unroll
            for (int n = 0; n < 4; ++n) {
                int row   = wc * 64 + n * 16 + l15;
                int kbyte = kk * 64 + l4 * 16;
                int addr  = row * 128 + (kbyte ^ ((row & 7) << 4));
                bfr[n] = *(const bf16x8*)(bbuf + addr);
            }
            #pragma unroll
            for (int m = 0; m < 4; ++m)
                #pragma unroll
                for (int n = 0; n < 4; ++n)
                    acc[m][n] = __builtin_amdgcn_mfma_f32_16x16x32_bf16(
                        af[m], bfr[n], acc[m][n], 0, 0, 0);
        }
        __builtin_amdgcn_s_barrier();                  // A reads done -> safe to overwrite
        asm volatile("s_waitcnt vmcnt(8)" ::: "memory");  // A(kn) landed
        WRITE_A();
        asm volatile("s_waitcnt vmcnt(0) lgkmcnt(0)" ::: "memory");  // B(kn) + writes
        __builtin_amdgcn_s_barrier();
    }

    // ---- C store (bf16) ----
    #pragma unroll
    for (int m = 0; m < 4; ++m)
        #pragma unroll
        for (int n = 0; n < 4; ++n)
            #pragma unroll
            for (int r = 0; r < 4; ++r) {
                int row = rowBase + wr * 64 + m * 16 + l4 * 4 + r;
                int col = colBase + wc * 64 + n * 16 + l15;
                Cv[(size_t)row * N + col] = f2b(acc[m][n][r]);
            }

    // ---- fused per-64-row-chunk EMA aggregate (wave's 64 rows = 1 chunk) --
    {
        const int bidx     = rowBase >> 12;
        const int chunkIdx = ((rowBase & 4095) >> 6) + wr;
        #pragma unroll
        for (int n = 0; n < 4; ++n) {
            int col = colBase + wc * 64 + n * 16 + l15;
            float qe = qv[col];
            float q2 = qe * qe, q4 = q2 * q2, q8 = q4 * q4, q16 = q8 * q8;
            float P = 0.0f;
            #pragma unroll
            for (int m = 3; m >= 0; --m) {
                f32x4 a = acc[m][n];
                float pm = ((a[3] * qe + a[2]) * qe + a[1]) * qe + a[0];
                P = P * q16 + pm;
            }
            float ql4 = (l4 & 1 ? q4 : 1.0f) * (l4 & 2 ? q8 : 1.0f);
            P *= ql4;
            P += __shfl_xor(P, 16, 64);
            P += __shfl_xor(P, 32, 64);
            if (l4 == 0)
                aggp[(((bidx << 6) | chunkIdx) << 10) + col] = P;
        }
    }
}

// ------------------------------- GEMM2: 128x128 m97 structure (proven) ----
template <int OUT_BF16>
__global__ __launch_bounds__(256) void gemm_bt(const ushort* __restrict__ A,
                                               const ushort* __restrict__ Bt,
                                               void* __restrict__ Cv,
                                               int M, int N, int K,
                                               int ncolShift) {
    __shared__ ushort smem[16384];
    const int tid  = threadIdx.x;
    const int lane = tid & 63;
    const int wid  = tid >> 6;
    const int wr   = wid >> 1, wc = wid & 1;
    const int l15  = lane & 15;
    const int l4   = lane >> 4;

    const int nwg   = gridDim.x;
    const int chunkw = nwg >> 3;
    const int flat  = (blockIdx.x & 7) * chunkw + (blockIdx.x >> 3);
    const int rowBase = (flat >> ncolShift) << 7;
    const int colBase = (flat & ((1 << ncolShift) - 1)) << 7;

    f32x4 acc[4][4] = {};

    const int nkb = K >> 6;
    for (int kb = 0; kb < nkb; ++kb) {
        #pragma unroll
        for (int r = 0; r < 4; ++r) {
            int c     = r * 256 + tid;
            int row   = c >> 3;
            int col16 = (c & 7) ^ (row & 7);
            const ushort* ga = A  + (size_t)(rowBase + row) * K + kb * 64 + col16 * 8;
            __builtin_amdgcn_global_load_lds(
                (const __attribute__((address_space(1))) void*)ga,
                (__attribute__((address_space(3))) void*)((char*)smem + c * 16),
                16, 0, 0);
            const ushort* gb = Bt + (size_t)(colBase + row) * K + kb * 64 + col16 * 8;
            __builtin_amdgcn_global_load_lds(
                (const __attribute__((address_space(1))) void*)gb,
                (__attribute__((address_space(3))) void*)((char*)smem + 16384 + c * 16),
                16, 0, 0);
        }
        __syncthreads();

        #pragma unroll
        for (int kk = 0; kk < 2; ++kk) {
            bf16x8 af[4], bfr[4];
            #pragma unroll
            for (int m = 0; m < 4; ++m) {
                int row   = wr * 64 + m * 16 + l15;
                int kbyte = kk * 64 + l4 * 16;
                int addr  = row * 128 + (kbyte ^ ((row & 7) << 4));
                af[m] = *(const bf16x8*)((const char*)smem + addr);
            }
            #pragma unroll
            for (int n = 0; n < 4; ++n) {
                int row   = wc * 64 + n * 16 + l15;
                int kbyte = kk * 64 + l4 * 16;
                int addr  = 16384 + row * 128 + (kbyte ^ ((row & 7) << 4));
                bfr[n] = *(const bf16x8*)((const char*)smem + addr);
            }
            #pragma unroll
            for (int m = 0; m < 4; ++m)
                #pragma unroll
                for (int n = 0; n < 4; ++n)
                    acc[m][n] = __builtin_amdgcn_mfma_f32_16x16x32_bf16(
                        af[m], bfr[n], acc[m][n], 0, 0, 0);
        }
        __syncthreads();
    }

    #pragma unroll
    for (int m = 0; m < 4; ++m)
        #pragma unroll
        for (int n = 0; n < 4; ++n)
            #pragma unroll
            for (int r = 0; r < 4; ++r) {
                int row = rowBase + wr * 64 + m * 16 + l4 * 4 + r;
                int col = colBase + wc * 64 + n * 16 + l15;
                if (OUT_BF16)
                    ((ushort*)Cv)[(size_t)row * N + col] = f2b(acc[m][n][r]);
                else
                    ((float*)Cv)[(size_t)row * N + col] = acc[m][n][r];
            }
}

// ---------------------------------------------------------------- scan ----
// In-place suffix EMA apply with cross-chunk carry from agg. 4 ch/thread.
__global__ void scan_apply_kernel(ushort* __restrict__ u,
                                  const float* __restrict__ pv,
                                  const float* __restrict__ qv,
                                  const float* __restrict__ agg) {
    int t = blockIdx.x * blockDim.x + threadIdx.x;   // 65536
    int e0 = (t & 255) * 4;
    int c  = (t >> 8) & 63;
    int b  = t >> 14;
    float4 qe4 = *(const float4*)(qv + e0);
    float4 pe4 = *(const float4*)(pv + e0);
    float qe[4] = {qe4.x, qe4.y, qe4.z, qe4.w};
    float pe[4] = {pe4.x, pe4.y, pe4.z, pe4.w};
    float qL[4], S[4], w[4];
    #pragma unroll
    for (int k = 0; k < 4; ++k) {
        float x = qe[k];
        #pragma unroll
        for (int s = 0; s < 6; ++s) x *= x;    // q^64
        qL[k] = x; S[k] = 0.0f; w[k] = 1.0f;
    }
    for (int cp = c + 1; cp < NCHUNK; ++cp) {
        float4 a = *(const float4*)(agg + (((b << 6) | cp) << 10) + e0);
        S[0] += w[0] * a.x;  w[0] *= qL[0];
        S[1] += w[1] * a.y;  w[1] *= qL[1];
        S[2] += w[2] * a.z;  w[2] *= qL[2];
        S[3] += w[3] * a.w;  w[3] *= qL[3];
    }
    ushort* up = u + ((size_t)(b * LSEQ + c * CHUNK) << 10) + e0;
    #pragma unroll 4
    for (int j = CHUNK - 1; j >= 0; --j) {
        ushort4 uv = *(ushort4*)(up + (size_t)j * EDIM);
        ushort4 ov;
        S[0] = b2f(uv.x) + qe[0] * S[0];  ov.x = f2b(pe[0] * S[0]);
        S[1] = b2f(uv.y) + qe[1] * S[1];  ov.y = f2b(pe[1] * S[1]);
        S[2] = b2f(uv.z) + qe[2] * S[2];  ov.z = f2b(pe[2] * S[2]);
        S[3] = b2f(uv.w) + qe[3] * S[3];  ov.w = f2b(pe[3] * S[3]);
        *(ushort4*)(up + (size_t)j * EDIM) = ov;
    }
}

// -------------------------------------------------------------- launch ----
extern "C" void kernel_launch(void* const* d_in, const int* in_sizes, int n_in,
                              void* d_out, int out_size, void* d_ws, size_t ws_size,
                              hipStream_t stream) {
    const float* emb  = (const float*)d_in[0];
    const float* la   = (const float*)d_in[1];
    const float* ld   = (const float*)d_in[2];
    const float* beta = (const float*)d_in[3];
    const float* eta  = (const float*)d_in[4];

    char* ws = (char*)d_ws;
    ushort* betaT = (ushort*)(ws);                    // 1 MB
    ushort* etaT  = (ushort*)(ws + 1048576);          // 1 MB
    ushort* u     = (ushort*)(ws + 2097152);          // 32 MB  u (in-place out)
    float*  p     = (float*) (ws + 35651584);         // 4 KB
    float*  q     = (float*) (ws + 35655680);         // 4 KB
    float*  agg   = (float*) (ws + 35659776);         // 1 MB [4][64][1024]

    prep_kernel<<<dim3(1025), dim3(256), 0, stream>>>(beta, eta, la, ld,
                                                      betaT, etaT, p, q);

    // u[16384,1024] = cvt_bf16(emb) @ betaT^T   (fused cvt + agg, 128^2 tile)
    gemm_f32a<<<dim3((MROWS / 128) * (EDIM / 128)), dim3(256), 0, stream>>>(
        emb, betaT, u, q, agg, MROWS, EDIM, DIM, 3);

    scan_apply_kernel<<<dim3(256), dim3(256), 0, stream>>>(u, p, q, agg);

    // y[16384,512] = u' @ etaT^T   (128^2, fp32 out)
    gemm_bt<0><<<dim3((MROWS / 128) * (OUTD / 128)), dim3(256), 0, stream>>>(
        u, etaT, d_out, MROWS, OUTD, EDIM, 2);
}

// Round 9
// 86.032 us; speedup vs baseline: 1.1059x; 1.1059x over previous
//
#include <hip/hip_runtime.h>
#include <hip/hip_bf16.h>

#define DIM      512
#define EDIM     1024
#define OUTD     512
#define BATCH    4
#define LSEQ     4096
#define MROWS    (BATCH * LSEQ)   // 16384
#define NCHUNK   64
#define CHUNK    (LSEQ / NCHUNK)  // 64

typedef __attribute__((ext_vector_type(8))) __bf16 bf16x8;
typedef __attribute__((ext_vector_type(4))) float  f32x4;

static __device__ __forceinline__ ushort f2b(float f) {
    uint x = __float_as_uint(f);
    x += 0x7fff + ((x >> 16) & 1);           // round-to-nearest-even
    return (ushort)(x >> 16);
}
static __device__ __forceinline__ float b2f(ushort u) {
    return __uint_as_float(((uint)u) << 16);
}
static __device__ __forceinline__ float sigmoidf(float x) {
    return 1.0f / (1.0f + expf(-x));
}
// 8x f32 -> bf16x8 via HW packed cvt (RNE), 4 instructions
static __device__ __forceinline__ bf16x8 cvt8(float4 lo, float4 hi) {
    int4 r;
    asm("v_cvt_pk_bf16_f32 %0, %1, %2" : "=v"(r.x) : "v"(lo.x), "v"(lo.y));
    asm("v_cvt_pk_bf16_f32 %0, %1, %2" : "=v"(r.y) : "v"(lo.z), "v"(lo.w));
    asm("v_cvt_pk_bf16_f32 %0, %1, %2" : "=v"(r.z) : "v"(hi.x), "v"(hi.y));
    asm("v_cvt_pk_bf16_f32 %0, %1, %2" : "=v"(r.w) : "v"(hi.z), "v"(hi.w));
    return __builtin_bit_cast(bf16x8, r);
}

// ---------------------------------------------------------------- prep ----
// blocks [0,512):    beta -> betaT (bf16, LDS 32x32 tiles)
// blocks [512,1024): eta  -> etaT  (bf16, LDS 32x32 tiles)
// block 1024: p,q from logits
__global__ void prep_kernel(const float* __restrict__ beta,
                            const float* __restrict__ eta,
                            const float* __restrict__ la,
                            const float* __restrict__ ld,
                            ushort* __restrict__ betaT,
                            ushort* __restrict__ etaT,
                            float* __restrict__ p,
                            float* __restrict__ q) {
    __shared__ float tf[32][33];
    int blk = blockIdx.x;
    if (blk < 512) {                         // beta transpose
        int tr = blk >> 5, tc = blk & 31;
        int r = threadIdx.x >> 3, c4 = (threadIdx.x & 7) * 4;
        float4 v = *(const float4*)(beta + (size_t)(tr * 32 + r) * EDIM + tc * 32 + c4);
        tf[r][c4 + 0] = v.x; tf[r][c4 + 1] = v.y;
        tf[r][c4 + 2] = v.z; tf[r][c4 + 3] = v.w;
        __syncthreads();
        ushort4 o;
        o.x = f2b(tf[c4 + 0][r]); o.y = f2b(tf[c4 + 1][r]);
        o.z = f2b(tf[c4 + 2][r]); o.w = f2b(tf[c4 + 3][r]);
        *(ushort4*)(betaT + (size_t)(tc * 32 + r) * DIM + tr * 32 + c4) = o;
    } else if (blk < 1024) {                 // eta transpose
        int tile = blk - 512;
        int tr = tile >> 4, tc = tile & 15;
        int r = threadIdx.x >> 3, c4 = (threadIdx.x & 7) * 4;
        float4 v = *(const float4*)(eta + (size_t)(tr * 32 + r) * OUTD + tc * 32 + c4);
        tf[r][c4 + 0] = v.x; tf[r][c4 + 1] = v.y;
        tf[r][c4 + 2] = v.z; tf[r][c4 + 3] = v.w;
        __syncthreads();
        ushort4 o;
        o.x = f2b(tf[c4 + 0][r]); o.y = f2b(tf[c4 + 1][r]);
        o.z = f2b(tf[c4 + 2][r]); o.w = f2b(tf[c4 + 3][r]);
        *(ushort4*)(etaT + (size_t)(tc * 32 + r) * EDIM + tr * 32 + c4) = o;
    } else {
        #pragma unroll
        for (int j = 0; j < 4; ++j) {
            int e = threadIdx.x * 4 + j;
            float a = sigmoidf(la[e]);
            float d = sigmoidf(ld[e]);
            p[e] = a;
            q[e] = 1.0f - a * d;
        }
    }
}

// -------------------- GEMM1: fp32-A via global_load_lds, cvt-on-read ------
// u[M,E] = cvt_bf16(emb[M,512]) @ betaT[E,512]^T, fused per-chunk agg.
// BM=BN=256, BK=32, 8 waves (2M x 4N), wave = 128x64 (acc[8][4]).
// Ring-3 LDS (3 x 48 KB): A fp32 [256 rows][128 B] XOR-granule-swizzled,
// B bf16 superrows [128][128 B] (R7's verbatim layout). ISSUE(t+2) placed
// right after the barrier closing tile t-1 (race-free, R7 placement);
// counted vmcnt(6) per tile keeps 2 tiles in flight (never drain mid-loop).
// A fragment = 2x ds_read_b128 fp32 + 4x v_cvt_pk_bf16_f32 (HW cvt, no
// f2b bit-math VALU storm - R8's failure mechanism).
#define MFMA_BF16 __builtin_amdgcn_mfma_f32_16x16x32_bf16
#define G1TILE 49152
#define G1NT   16

__global__ __launch_bounds__(512, 2) void gemm1_f32a(
        const float* __restrict__ Af, const ushort* __restrict__ Bt,
        ushort* __restrict__ Cv, const float* __restrict__ qv,
        float* __restrict__ aggp) {
    extern __shared__ __align__(16) char smem[];   // 147456 bytes, 3 slots
    const int tid  = threadIdx.x;
    const int lane = tid & 63;
    const int wid  = tid >> 6;       // 0..7
    const int wr   = wid >> 2;       // 0..1  (M half: 128 rows)
    const int wc   = wid & 3;        // 0..3  (N quarter: 64 cols)
    const int l15  = lane & 15;
    const int l4   = lane >> 4;

    const int nwg  = gridDim.x;      // 256
    const int flat = ((int)blockIdx.x & 7) * (nwg >> 3) + ((int)blockIdx.x >> 3);
    const int rowBase = (flat >> 2) << 8;        // M/256 = 64 panels
    const int colBase = (flat & 3) << 8;         // E/256 = 4 panels

    // ---- A staging map: 2048 chunks of 16B; chunk c: row=c>>3 (0..255),
    //      stored granule g=c&7 holds logical granule g^(row&7) -> fp32 col.
    const int ar[4] = { (0 * 512 + tid) >> 3, (1 * 512 + tid) >> 3,
                        (2 * 512 + tid) >> 3, (3 * 512 + tid) >> 3 };
    // ---- B staging map (R7 superrow): c: sr=c>>3, sl=(c&7)^(sr&7),
    //      row = 2*sr + (sl>>2), k = (sl&3)*8.
    const int srT  = tid >> 3;
    const int slT  = (tid & 7) ^ (srT & 7);
    const int rowT = 2 * srT + (slT >> 2);
    const int kT   = (slT & 3) * 8;

    const float*  gA[4];
    #pragma unroll
    for (int r = 0; r < 4; ++r) {
        int c  = r * 512 + tid;
        int sl = (c & 7) ^ (ar[r] & 7);
        gA[r] = Af + (size_t)(rowBase + ar[r]) * DIM + sl * 4;
    }
    const ushort* gB0 = Bt + (size_t)(colBase + rowT) * DIM + kT;          // rows 0-127
    const ushort* gB1 = gB0 + (size_t)128 * DIM;                           // rows 128-255

    // ---- fragment read bases
    const int sA  = l15 & 7;
    const int aB  = (wr * 128 + l15) * 128;
    const int a0  = aB + (((l4 * 2)     ^ sA) << 4);
    const int a1  = aB + (((l4 * 2 + 1) ^ sA) << 4);
    const int l7  = l15 >> 1;
    const int sx  = ((((l15 & 1) * 4 + l4) ^ l7)) << 4;
    const int bB  = 32768 + (wc * 32 + l7) * 128 + sx;   // + n*1024

    f32x4 acc[8][4] = {};
    bf16x8 af[8], bfr[4];

    auto ISSUE = [&](int t, char* slot) {
        const size_t ko = (size_t)t * 32;
        #pragma unroll
        for (int r = 0; r < 4; ++r)
            __builtin_amdgcn_global_load_lds(
                (const __attribute__((address_space(1))) void*)(gA[r] + ko),
                (__attribute__((address_space(3))) void*)(slot + (r * 512 + tid) * 16),
                16, 0, 0);
        __builtin_amdgcn_global_load_lds(
            (const __attribute__((address_space(1))) void*)(gB0 + ko),
            (__attribute__((address_space(3))) void*)(slot + 32768 + tid * 16), 16, 0, 0);
        __builtin_amdgcn_global_load_lds(
            (const __attribute__((address_space(1))) void*)(gB1 + ko),
            (__attribute__((address_space(3))) void*)(slot + 40960 + tid * 16), 16, 0, 0);
    };

    char* slot0 = smem;                // tile t
    char* slot1 = smem + G1TILE;       // tile t+1
    char* slot2 = smem + 2 * G1TILE;   // tile t+2 (issue target)

    // ---- prologue: 2 tiles in flight, wait tile 0
    ISSUE(0, slot0);
    ISSUE(1, slot1);
    asm volatile("s_waitcnt vmcnt(6)" ::: "memory");
    __builtin_amdgcn_s_barrier();

    for (int t = 0; t < G1NT; ++t) {
        if (t + 2 < G1NT) ISSUE(t + 2, slot2);   // race-free: after barrier
        const char* sm = slot0;
        #pragma unroll
        for (int n = 0; n < 4; ++n)
            bfr[n] = *(const bf16x8*)(sm + bB + n * 1024);
        #pragma unroll
        for (int m = 0; m < 8; ++m) {
            float4 lo = *(const float4*)(sm + a0 + m * 2048);
            float4 hi = *(const float4*)(sm + a1 + m * 2048);
            af[m] = cvt8(lo, hi);
        }
        __builtin_amdgcn_s_setprio(1);
        #pragma unroll
        for (int m = 0; m < 8; ++m)
            #pragma unroll
            for (int n = 0; n < 4; ++n)
                acc[m][n] = MFMA_BF16(af[m], bfr[n], acc[m][n], 0, 0, 0);
        __builtin_amdgcn_s_setprio(0);
        if (t + 2 < G1NT)
            asm volatile("s_waitcnt vmcnt(6)" ::: "memory");   // tile t+1 landed
        else if (t + 1 < G1NT)
            asm volatile("s_waitcnt vmcnt(0)" ::: "memory");
        if (t + 1 < G1NT) __builtin_amdgcn_s_barrier();
        char* tmp = slot0; slot0 = slot1; slot1 = slot2; slot2 = tmp;
    }

    // ---- C store (bf16 u): row = m*16 + 4*l4 + r, col = n*16 + l15 ----
    #pragma unroll
    for (int m = 0; m < 8; ++m)
        #pragma unroll
        for (int n = 0; n < 4; ++n)
            #pragma unroll
            for (int r = 0; r < 4; ++r) {
                int row = rowBase + wr * 128 + m * 16 + l4 * 4 + r;
                int col = colBase + wc * 64 + n * 16 + l15;
                Cv[(size_t)row * EDIM + col] = f2b(acc[m][n][r]);
            }

    // ---- fused per-64-row-chunk EMA aggregates (2 chunks per wave) ----
    {
        const int bidx = rowBase >> 12;
        const int chunkBase = ((rowBase & 4095) >> 6) + wr * 2;
        #pragma unroll
        for (int h = 0; h < 2; ++h) {
            #pragma unroll
            for (int n = 0; n < 4; ++n) {
                int col = colBase + wc * 64 + n * 16 + l15;
                float qe = qv[col];
                float q2 = qe * qe, q4 = q2 * q2, q8 = q4 * q4, q16 = q8 * q8;
                float P = 0.0f;
                #pragma unroll
                for (int m = 3; m >= 0; --m) {
                    f32x4 a = acc[h * 4 + m][n];
                    float pm = ((a[3] * qe + a[2]) * qe + a[1]) * qe + a[0];
                    P = P * q16 + pm;
                }
                float ql4 = (l4 & 1 ? q4 : 1.0f) * (l4 & 2 ? q8 : 1.0f);
                P *= ql4;
                P += __shfl_xor(P, 16, 64);
                P += __shfl_xor(P, 32, 64);
                if (l4 == 0)
                    aggp[(((bidx << 6) | (chunkBase + h)) << 10) + col] = P;
            }
        }
    }
}

// ----------------------------- GEMM2: ring-4 (R7 verbatim, bf16) ----------
template <int KDIM, int BN, int NSHIFT, int OUT_BF16>
__global__ __launch_bounds__(512, 2) void gemmr4(const ushort* __restrict__ A,
                                                 const ushort* __restrict__ Bt,
                                                 void* __restrict__ Cv,
                                                 int N) {
    constexpr int NF   = BN / 64;
    constexpr int LB   = BN / 128;
    constexpr int TILE = 16384 + BN * 64;
    constexpr int NT   = KDIM / 32;

    extern __shared__ __align__(16) char smem[];
    const int tid  = threadIdx.x;
    const int lane = tid & 63;
    const int wid  = tid >> 6;
    const int wr   = wid >> 2;
    const int wc   = wid & 3;
    const int l15  = lane & 15;
    const int l4   = lane >> 4;

    const int nwg  = gridDim.x;
    const int flat = ((int)blockIdx.x & 7) * (nwg >> 3) + ((int)blockIdx.x >> 3);
    const int rowBase = (flat >> NSHIFT) << 8;
    const int colBase = (flat & ((1 << NSHIFT) - 1)) * BN;

    const int srT = tid >> 3;
    const int slT = (tid & 7) ^ (srT & 7);
    const int rowT = 2 * srT + (slT >> 2);
    const int kT   = (slT & 3) * 8;
    const ushort* gA0 = A  + (size_t)(rowBase + rowT) * KDIM + kT;
    const ushort* gA1 = gA0 + (size_t)128 * KDIM;
    const ushort* gB0 = Bt + (size_t)(colBase + rowT) * KDIM + kT;
    const ushort* gB1 = gB0 + (size_t)128 * KDIM;

    const int l7 = l15 >> 1;
    const int sx = ((((l15 & 1) * 4 + l4) ^ l7)) << 4;
    const int aBase = (wr * 64 + l7) * 128 + sx;
    const int bBase = 16384 + (wc * (BN / 8) + l7) * 128 + sx;

    f32x4 acc[8][NF] = {};
    bf16x8 af[8], bfr[NF];

    auto ISSUE = [&](int t) {
        const int boff = (t & 3) * TILE;
        const size_t ko = (size_t)t * 32;
        __builtin_amdgcn_global_load_lds(
            (const __attribute__((address_space(1))) void*)(gA0 + ko),
            (__attribute__((address_space(3))) void*)(smem + boff + tid * 16), 16, 0, 0);
        __builtin_amdgcn_global_load_lds(
            (const __attribute__((address_space(1))) void*)(gA1 + ko),
            (__attribute__((address_space(3))) void*)(smem + boff + 8192 + tid * 16), 16, 0, 0);
        __builtin_amdgcn_global_load_lds(
            (const __attribute__((address_space(1))) void*)(gB0 + ko),
            (__attribute__((address_space(3))) void*)(smem + boff + 16384 + tid * 16), 16, 0, 0);
        if (LB == 2)
            __builtin_amdgcn_global_load_lds(
                (const __attribute__((address_space(1))) void*)(gB1 + ko),
                (__attribute__((address_space(3))) void*)(smem + boff + 24576 + tid * 16), 16, 0, 0);
    };

    ISSUE(0); ISSUE(1); ISSUE(2);
    if (LB == 2) asm volatile("s_waitcnt vmcnt(8)" ::: "memory");
    else         asm volatile("s_waitcnt vmcnt(6)" ::: "memory");
    __builtin_amdgcn_s_barrier();

    for (int t = 0; t < NT; ++t) {
        if (t + 3 < NT) ISSUE(t + 3);
        const char* sm = smem + (t & 3) * TILE;
        #pragma unroll
        for (int m = 0; m < 8; ++m)
            af[m] = *(const bf16x8*)(sm + aBase + m * 1024);
        #pragma unroll
        for (int n = 0; n < NF; ++n)
            bfr[n] = *(const bf16x8*)(sm + bBase + n * 1024);
        __builtin_amdgcn_s_setprio(1);
        #pragma unroll
        for (int m = 0; m < 8; ++m)
            #pragma unroll
            for (int n = 0; n < NF; ++n)
                acc[m][n] = MFMA_BF16(af[m], bfr[n], acc[m][n], 0, 0, 0);
        __builtin_amdgcn_s_setprio(0);
        if (t < NT - 3) {
            if (LB == 2) asm volatile("s_waitcnt vmcnt(8)" ::: "memory");
            else         asm volatile("s_waitcnt vmcnt(6)" ::: "memory");
        } else if (t == NT - 3) {
            if (LB == 2) asm volatile("s_waitcnt vmcnt(4)" ::: "memory");
            else         asm volatile("s_waitcnt vmcnt(3)" ::: "memory");
        } else if (t == NT - 2) {
            asm volatile("s_waitcnt vmcnt(0)" ::: "memory");
        }
        if (t < NT - 1) __builtin_amdgcn_s_barrier();
    }

    #pragma unroll
    for (int m = 0; m < 8; ++m)
        #pragma unroll
        for (int n = 0; n < NF; ++n)
            #pragma unroll
            for (int r = 0; r < 4; ++r) {
                int row = rowBase + wr * 128 + m * 16 + l4 * 4 + r;
                int col = colBase + wc * (BN / 4) + n * 16 + l15;
                if (OUT_BF16)
                    ((ushort*)Cv)[(size_t)row * N + col] = f2b(acc[m][n][r]);
                else
                    ((float*)Cv)[(size_t)row * N + col] = acc[m][n][r];
            }
}

// ---------------------------------------------------------------- scan ----
// In-place suffix EMA apply with cross-chunk carry from agg. 4 ch/thread.
__global__ void scan_apply_kernel(ushort* __restrict__ u,
                                  const float* __restrict__ pv,
                                  const float* __restrict__ qv,
                                  const float* __restrict__ agg) {
    int t = blockIdx.x * blockDim.x + threadIdx.x;   // 65536
    int e0 = (t & 255) * 4;
    int c  = (t >> 8) & 63;
    int b  = t >> 14;
    float4 qe4 = *(const float4*)(qv + e0);
    float4 pe4 = *(const float4*)(pv + e0);
    float qe[4] = {qe4.x, qe4.y, qe4.z, qe4.w};
    float pe[4] = {pe4.x, pe4.y, pe4.z, pe4.w};
    float qL[4], S[4], w[4];
    #pragma unroll
    for (int k = 0; k < 4; ++k) {
        float x = qe[k];
        #pragma unroll
        for (int s = 0; s < 6; ++s) x *= x;    // q^64
        qL[k] = x; S[k] = 0.0f; w[k] = 1.0f;
    }
    for (int cp = c + 1; cp < NCHUNK; ++cp) {
        float4 a = *(const float4*)(agg + (((b << 6) | cp) << 10) + e0);
        S[0] += w[0] * a.x;  w[0] *= qL[0];
        S[1] += w[1] * a.y;  w[1] *= qL[1];
        S[2] += w[2] * a.z;  w[2] *= qL[2];
        S[3] += w[3] * a.w;  w[3] *= qL[3];
    }
    ushort* up = u + ((size_t)(b * LSEQ + c * CHUNK) << 10) + e0;
    #pragma unroll 4
    for (int j = CHUNK - 1; j >= 0; --j) {
        ushort4 uv = *(ushort4*)(up + (size_t)j * EDIM);
        ushort4 ov;
        S[0] = b2f(uv.x) + qe[0] * S[0];  ov.x = f2b(pe[0] * S[0]);
        S[1] = b2f(uv.y) + qe[1] * S[1];  ov.y = f2b(pe[1] * S[1]);
        S[2] = b2f(uv.z) + qe[2] * S[2];  ov.z = f2b(pe[2] * S[2]);
        S[3] = b2f(uv.w) + qe[3] * S[3];  ov.w = f2b(pe[3] * S[3]);
        *(ushort4*)(up + (size_t)j * EDIM) = ov;
    }
}

// -------------------------------------------------------------- launch ----
extern "C" void kernel_launch(void* const* d_in, const int* in_sizes, int n_in,
                              void* d_out, int out_size, void* d_ws, size_t ws_size,
                              hipStream_t stream) {
    const float* emb  = (const float*)d_in[0];
    const float* la   = (const float*)d_in[1];
    const float* ld   = (const float*)d_in[2];
    const float* beta = (const float*)d_in[3];
    const float* eta  = (const float*)d_in[4];

    char* ws = (char*)d_ws;
    ushort* betaT = (ushort*)(ws);                    // 1 MB
    ushort* etaT  = (ushort*)(ws + 1048576);          // 1 MB
    ushort* u     = (ushort*)(ws + 2097152);          // 32 MB  u (in-place out)
    float*  p     = (float*) (ws + 35651584);         // 4 KB
    float*  q     = (float*) (ws + 35655680);         // 4 KB
    float*  agg   = (float*) (ws + 35659776);         // 1 MB [4][64][1024]

    (void)hipFuncSetAttribute((const void*)gemm1_f32a,
                              hipFuncAttributeMaxDynamicSharedMemorySize, 147456);
    (void)hipFuncSetAttribute((const void*)gemmr4<1024, 128, 2, 0>,
                              hipFuncAttributeMaxDynamicSharedMemorySize, 98304);

    prep_kernel<<<dim3(1025), dim3(256), 0, stream>>>(beta, eta, la, ld,
                                                      betaT, etaT, p, q);

    // u[16384,1024] = cvt_bf16(emb) @ betaT^T  (fp32-A gload_lds, cvt-on-read)
    gemm1_f32a<<<dim3(256), dim3(512), 147456, stream>>>(emb, betaT, u, q, agg);

    scan_apply_kernel<<<dim3(256), dim3(256), 0, stream>>>(u, p, q, agg);

    // y[16384,512] = u' @ etaT^T   (ring-4, fp32 out)
    gemmr4<1024, 128, 2, 0><<<dim3(256), dim3(512), 98304, stream>>>(
        u, etaT, d_out, OUTD);
}